// Round 3
// baseline (297.924 us; speedup 1.0000x reference)
//
#include <hip/hip_runtime.h>
#include <math.h>

// Problem constants (from reference)
#define D_SVG 256
#define N_TYPE 10
#define N_PAR 12
#define F_TOT (D_SVG + N_TYPE + N_PAR)        // 278
#define ROWS_PER_BLOCK 64
#define THREADS 256
#define N4_PER_BLOCK (ROWS_PER_BLOCK * F_TOT / 4)   // 4448 float4 per tensor per block
#define SEC (N_TYPE + N_PAR)                  // 22 floats/row stashed to LDS
#define SECP 23                               // padded stride (odd -> conflict-free)

// ws layout:
//   float4   part[2048]   @ 0       (x=svg_sq, y=par12_sq, z=nll, w=par_corr)
//   unsigned bitmap[4096] @ 32768   (bit r of word w = row 32*w+r valid)

// ---------------- Prekernel: validity bitmap ----------------
__global__ __launch_bounds__(256) void bitmap_kernel(const float* __restrict__ target,
                                                     unsigned* __restrict__ bitmap) {
    const int tid = threadIdx.x;
    const long r = (long)blockIdx.x * 256 + tid;           // one row per thread
    const bool valid = (target[r * F_TOT + D_SVG] != -1.0f);
    unsigned long long bal = __ballot(valid);
    const int lane = tid & 63, wv = tid >> 6;
    if (lane == 0)  bitmap[blockIdx.x * 8 + wv * 2]     = (unsigned)bal;
    if (lane == 32) bitmap[blockIdx.x * 8 + wv * 2 + 1] = (unsigned)(bal >> 32);
}

// ---------------- Fused kernel: streaming MSE + in-LDS CE/correction ----------------
// One block = 64 rows. Flat strided loop with 8-deep unrolled chunks: 16 unconditional
// global loads in flight per wave-iteration (the round-2 version compiled to 44 VGPRs
// -> the compiler had re-batched the staged loads into tiny load/wait groups, MLP~1,
// 2.5 TB/s). Validity is one 64-bit shift of a wave-uniform bitmap word.
__global__ __launch_bounds__(THREADS) void fused_kernel(const float* __restrict__ input,
                                                        const float* __restrict__ target,
                                                        const unsigned* __restrict__ bitmap,
                                                        float4* __restrict__ part) {
    __shared__ float s_in[ROWS_PER_BLOCK][SECP];
    __shared__ float s_tg[ROWS_PER_BLOCK][SECP];
    __shared__ float sred[4][4];
    const int tid  = threadIdx.x;
    const int lane = tid & 63, wave = tid >> 6;

    // wave-uniform 64-bit validity of this block's 64 rows (8B-aligned: offset 32768+8*blk)
    const unsigned long long b =
        ((const unsigned long long*)bitmap)[blockIdx.x];

    if (b == 0ull) {    // all 64 rows padded: handled in closed form at the reduce
        if (tid == 0) part[blockIdx.x] = make_float4(0.f, 0.f, 0.f, 0.f);
        return;
    }

    const long row0 = (long)blockIdx.x * ROWS_PER_BLOCK;

    // Padding is suffix-contiguous per batch and 512 % 64 == 0 (blocks never cross a
    // batch), so b is a prefix mask: bound the loop at the last valid row. The
    // per-element validity check is KEPT, so correctness never depends on this.
    const unsigned k = (unsigned)__popcll(b);
    const unsigned long long pre = (k == 64u) ? ~0ull : ((1ull << k) - 1ull);
    const unsigned n4v = (b == pre) ? ((k * (unsigned)F_TOT + 3u) >> 2)
                                    : (unsigned)N4_PER_BLOCK;

    const float4* __restrict__ in4p = (const float4*)(input  + row0 * F_TOT);
    const float4* __restrict__ tg4p = (const float4*)(target + row0 * F_TOT);

    float svg = 0.0f, par = 0.0f;

    // 278 % 4 == 2: a float4 crosses a row boundary only between elems 1|2.
    auto accum = [&](unsigned idx, float4 ivv, float4 tvv) {
        unsigned e0 = idx * 4u;
        unsigned ra = e0 / (unsigned)F_TOT;            // compiler magic-mul
        unsigned rb = (e0 + 2u) / (unsigned)F_TOT;
        unsigned fa = e0 - ra * (unsigned)F_TOT;
        unsigned fb = (e0 + 2u) - rb * (unsigned)F_TOT;
        unsigned vA = (unsigned)(b >> ra) & 1u;        // single 64-bit shift
        unsigned vB = (unsigned)(b >> rb) & 1u;
        float xs[4] = {ivv.x, ivv.y, ivv.z, ivv.w};
        float ts[4] = {tvv.x, tvv.y, tvv.z, tvv.w};
        #pragma unroll
        for (int j = 0; j < 4; ++j) {
            unsigned row  = (j < 2) ? ra : rb;
            unsigned feat = ((j < 2) ? fa : fb) + (unsigned)(j & 1);
            unsigned v    = (j < 2) ? vA : vB;
            float d = xs[j] - ts[j];
            float sq = d * d;
            svg += (v && feat < D_SVG) ? sq : 0.0f;
            par += (v && feat >= D_SVG + N_TYPE) ? sq : 0.0f;
            if (feat >= D_SVG) {                       // stash section for CE phase
                s_in[row][feat - D_SVG] = xs[j];
                s_tg[row][feat - D_SVG] = ts[j];
            }
        }
    };

    // main loop: 8-deep chunks, 16 unconditional loads in flight per wave-iter
    unsigned idx = (unsigned)tid;
    for (; idx + 7u * THREADS < n4v; idx += 8u * THREADS) {
        float4 a[8], t[8];
        #pragma unroll
        for (int u = 0; u < 8; ++u) a[u] = in4p[idx + u * THREADS];
        #pragma unroll
        for (int u = 0; u < 8; ++u) t[u] = tg4p[idx + u * THREADS];
        #pragma unroll
        for (int u = 0; u < 8; ++u) accum(idx + u * THREADS, a[u], t[u]);
    }
    for (; idx < n4v; idx += THREADS) accum(idx, in4p[idx], tg4p[idx]);

    __syncthreads();    // stash complete

    // ---- per-row CE + param correction from LDS (wave 0, one row per lane) ----
    float nll = 0.0f, corr = 0.0f;
    if (tid < ROWS_PER_BLOCK && ((b >> tid) & 1ull)) {
        float tt[N_TYPE], l[N_TYPE];
        #pragma unroll
        for (int j = 0; j < N_TYPE; ++j) { tt[j] = s_tg[tid][j]; l[j] = s_in[tid][j]; }
        int ti = 0; float best = tt[0];
        #pragma unroll
        for (int j = 1; j < N_TYPE; ++j) { if (tt[j] > best) { best = tt[j]; ti = j; } }
        float m = l[0];
        #pragma unroll
        for (int j = 1; j < N_TYPE; ++j) m = fmaxf(m, l[j]);
        float s = 0.0f;
        #pragma unroll
        for (int j = 0; j < N_TYPE; ++j) s += __expf(l[j] - m);
        nll = __logf(s) + m - l[ti];
        // replaced params {ti, ti+1, ti+2} (ti<=9, no wrap) contribute 0 in the
        // reference; the bulk sum covers all 12 -> record the subtraction.
        #pragma unroll
        for (int j = 0; j < 3; ++j) {
            float d = s_in[tid][N_TYPE + ti + j] - s_tg[tid][N_TYPE + ti + j];
            corr += d * d;
        }
    }

    // ---- block reduce (svg, par, nll, corr) ----
    float vals[4] = {svg, par, nll, corr};
    #pragma unroll
    for (int v = 0; v < 4; ++v) {
        float x = vals[v];
        #pragma unroll
        for (int off = 32; off > 0; off >>= 1) x += __shfl_down(x, off, 64);
        vals[v] = x;
    }
    if (lane == 0) {
        #pragma unroll
        for (int v = 0; v < 4; ++v) sred[wave][v] = vals[v];
    }
    __syncthreads();
    if (tid == 0) {
        float s0 = sred[0][0] + sred[1][0] + sred[2][0] + sred[3][0];
        float s1 = sred[0][1] + sred[1][1] + sred[2][1] + sred[3][1];
        float s2 = sred[0][2] + sred[1][2] + sred[2][2] + sred[3][2];
        float s3 = sred[0][3] + sred[1][3] + sred[2][3] + sred[3][3];
        part[blockIdx.x] = make_float4(s0, s1, s2, s3);
    }
}

// ---------------- Final reduce + loss composition ----------------
__global__ __launch_bounds__(256) void loss_final(const float4* __restrict__ part,
                                                  const unsigned* __restrict__ bitmap,
                                                  float* __restrict__ out,
                                                  int nb, int nw, int nrows) {
    __shared__ double sred[4][5];
    const int tid = threadIdx.x;
    double svg = 0.0, par = 0.0, nll = 0.0, corr = 0.0, cnt = 0.0;
    for (int i = tid; i < nb; i += 256) {
        float4 v = part[i];
        svg += v.x; par += v.y; nll += v.z; corr += v.w;
    }
    for (int i = tid; i < nw; i += 256)
        cnt += (double)__popc(bitmap[i]);
    double vals[5] = {svg, par, nll, corr, cnt};
    #pragma unroll
    for (int v = 0; v < 5; ++v) {
        double x = vals[v];
        #pragma unroll
        for (int off = 32; off > 0; off >>= 1) x += __shfl_down(x, off, 64);
        vals[v] = x;
    }
    const int wave = tid >> 6, lane = tid & 63;
    if (lane == 0) {
        #pragma unroll
        for (int v = 0; v < 5; ++v) sred[wave][v] = vals[v];
    }
    __syncthreads();
    if (tid == 0) {
        double S[5];
        #pragma unroll
        for (int v = 0; v < 5; ++v)
            S[v] = sred[0][v] + sred[1][v] + sred[2][v] + sred[3][v];
        double npad = (double)nrows - S[4];
        // padded rows: every svg/par element contributes (-100-(-1))^2 = 9801
        double svg_t = S[0] + 9801.0 * D_SVG * npad;
        double par_t = S[1] - S[3] + 9801.0 * N_PAR * npad;
        double loss = 10.0 * svg_t / ((double)nrows * D_SVG)
                    + 0.1  * S[2] / fmax(S[4], 1.0)
                    + 1.0  * par_t / ((double)nrows * N_PAR);
        out[0] = (float)loss;
    }
}

extern "C" void kernel_launch(void* const* d_in, const int* in_sizes, int n_in,
                              void* d_out, int out_size, void* d_ws, size_t ws_size,
                              hipStream_t stream) {
    const float* input  = (const float*)d_in[0];
    const float* target = (const float*)d_in[1];
    // d_in[2] (padding mask) unused: padded <=> target[row*278+256] == -1.0f
    float* out = (float*)d_out;

    const int nrows = in_sizes[0] / F_TOT;      // 131072 (divisible by 256)
    const int blk   = nrows / ROWS_PER_BLOCK;   // 2048
    const int nw    = nrows / 32;               // 4096 bitmap words
    const int blk_m = nrows / 256;              // 512

    float4*   part   = (float4*)d_ws;
    unsigned* bitmap = (unsigned*)((char*)d_ws + (size_t)blk * sizeof(float4));

    bitmap_kernel<<<blk_m, 256, 0, stream>>>(target, bitmap);
    fused_kernel<<<blk, THREADS, 0, stream>>>(input, target, bitmap, part);
    loss_final<<<1, 256, 0, stream>>>(part, bitmap, out, blk, nw, nrows);
}

// Round 4
// 297.245 us; speedup vs baseline: 1.0023x; 1.0023x over previous
//
#include <hip/hip_runtime.h>
#include <math.h>

// Problem constants (from reference)
#define D_SVG 256
#define N_TYPE 10
#define N_PAR 12
#define F_TOT 278
#define ROWS_PER_BLOCK 64
#define THREADS 256
#define N4_PER_BLOCK (ROWS_PER_BLOCK * F_TOT / 4)   // 4448 float4 per tensor per block
#define SECP 23                               // padded LDS stride (odd -> conflict-free)

// ws layout:
//   float4   part[2048]   @ 0       (x=svg_sq, y=par12_sq, z=nll, w=par_corr)
//   unsigned bitmap[4096] @ 32768   (bit r of word w = row 32*w+r valid)

// ---------------- Prekernel: validity bitmap ----------------
__global__ __launch_bounds__(256) void bitmap_kernel(const float* __restrict__ target,
                                                     unsigned* __restrict__ bitmap) {
    const int tid = threadIdx.x;
    const long r = (long)blockIdx.x * 256 + tid;           // one row per thread
    const bool valid = (target[r * F_TOT + D_SVG] != -1.0f);
    unsigned long long bal = __ballot(valid);
    const int lane = tid & 63, wv = tid >> 6;
    if (lane == 0)  bitmap[blockIdx.x * 8 + wv * 2]     = (unsigned)bal;
    if (lane == 32) bitmap[blockIdx.x * 8 + wv * 2 + 1] = (unsigned)(bal >> 32);
}

// ---------------- Fused kernel ----------------
// Main loop is a pure streaming d^2 reduction with ZERO per-element masking:
// within the prefix-bounded trip count every element belongs to a valid row
// (<=2-element overshoot corrected by thread 0). Rounds 1-3 all plateaued at
// ~90us because ~50 VALU instr/pair (magic-divs + selects + LDS stash) capped
// consumption at ~3.3 B/cy/CU; this loop is ~12 instr/pair.
// svg is recovered as S_all - S_type - S_par via a tiny L1-hot section pass.
__global__ __launch_bounds__(THREADS) void fused_kernel(const float* __restrict__ input,
                                                        const float* __restrict__ target,
                                                        const unsigned* __restrict__ bitmap,
                                                        float4* __restrict__ part) {
    __shared__ float s_in[ROWS_PER_BLOCK][SECP];
    __shared__ float s_tg[ROWS_PER_BLOCK][SECP];
    __shared__ float sred[4][4];
    const int tid  = threadIdx.x;
    const int lane = tid & 63, wave = tid >> 6;

    // wave-uniform 64-bit validity of this block's 64 rows
    const unsigned long long b = ((const unsigned long long*)bitmap)[blockIdx.x];

    if (b == 0ull) {    // all 64 rows padded: handled in closed form at the reduce
        if (tid == 0) part[blockIdx.x] = make_float4(0.f, 0.f, 0.f, 0.f);
        return;
    }

    const long row0 = (long)blockIdx.x * ROWS_PER_BLOCK;

    // Padding is suffix-contiguous per batch and 512 % 64 == 0, so b is a prefix
    // mask on this data; the slow path below keeps correctness if it ever isn't.
    const unsigned k = (unsigned)__popcll(b);
    const unsigned long long pre = (k == 64u) ? ~0ull : ((1ull << k) - 1ull);
    const bool fast = (b == pre);
    const unsigned n4v = fast ? ((k * (unsigned)F_TOT + 3u) >> 2)
                              : (unsigned)N4_PER_BLOCK;

    const float4* __restrict__ in4p = (const float4*)(input  + row0 * F_TOT);
    const float4* __restrict__ tg4p = (const float4*)(target + row0 * F_TOT);

    float sall = 0.0f;   // sum of d^2 over ALL features of valid rows

    if (fast) {
        unsigned idx = (unsigned)tid;
        for (; idx + 7u * THREADS < n4v; idx += 8u * THREADS) {
            float4 a[8], t[8];
            #pragma unroll
            for (int u = 0; u < 8; ++u) a[u] = in4p[idx + u * THREADS];
            #pragma unroll
            for (int u = 0; u < 8; ++u) t[u] = tg4p[idx + u * THREADS];
            #pragma unroll
            for (int u = 0; u < 8; ++u) {
                float dx = a[u].x - t[u].x, dy = a[u].y - t[u].y;
                float dz = a[u].z - t[u].z, dw = a[u].w - t[u].w;
                sall = fmaf(dx, dx, sall); sall = fmaf(dy, dy, sall);
                sall = fmaf(dz, dz, sall); sall = fmaf(dw, dw, sall);
            }
        }
        for (; idx < n4v; idx += THREADS) {
            float4 a = in4p[idx], t = tg4p[idx];
            float dx = a.x - t.x, dy = a.y - t.y, dz = a.z - t.z, dw = a.w - t.w;
            sall = fmaf(dx, dx, sall); sall = fmaf(dy, dy, sall);
            sall = fmaf(dz, dz, sall); sall = fmaf(dw, dw, sall);
        }
        // overshoot: k odd -> last float4 covered feats {0,1} of first invalid row
        if (tid == 0 && (k & 1u) && k < 64u) {
            const float* ip = input  + (row0 + k) * F_TOT;
            const float* tp = target + (row0 + k) * F_TOT;
            float d0 = ip[0] - tp[0], d1 = ip[1] - tp[1];   // L1-hot
            sall -= d0 * d0 + d1 * d1;
        }
    } else {
        // defensive masked path (never taken on prefix-padded data)
        for (unsigned idx = (unsigned)tid; idx < (unsigned)N4_PER_BLOCK; idx += THREADS) {
            float4 a = in4p[idx], t = tg4p[idx];
            unsigned e0 = idx * 4u;
            unsigned ra = e0 / (unsigned)F_TOT;          // 278%4==2: split 1|2 only
            unsigned rb = (e0 + 2u) / (unsigned)F_TOT;
            float vA = (float)((unsigned)(b >> ra) & 1u);
            float vB = (float)((unsigned)(b >> rb) & 1u);
            float dx = a.x - t.x, dy = a.y - t.y, dz = a.z - t.z, dw = a.w - t.w;
            sall = fmaf(vA * dx, dx, sall); sall = fmaf(vA * dy, dy, sall);
            sall = fmaf(vB * dz, dz, sall); sall = fmaf(vB * dw, dw, sall);
        }
    }

    // ---- section pass: type/par sums + LDS stash (L1/L2-hot re-read, 88B/row) ----
    float stype = 0.0f, spar = 0.0f;
    {
        const int r = tid >> 2, c = tid & 3;
        if ((b >> r) & 1ull) {
            const float2* __restrict__ ip2 = (const float2*)(input  + (row0 + r) * F_TOT + D_SVG);
            const float2* __restrict__ tp2 = (const float2*)(target + (row0 + r) * F_TOT + D_SVG);
            #pragma unroll
            for (int m = 0; m < 3; ++m) {
                int j = c + 4 * m;                        // 11 float2: j<5 type, j>=5 par
                if (j < 11) {
                    float2 iv = ip2[j], tv = tp2[j];
                    s_in[r][2*j] = iv.x; s_in[r][2*j + 1] = iv.y;
                    s_tg[r][2*j] = tv.x; s_tg[r][2*j + 1] = tv.y;
                    float d0 = iv.x - tv.x, d1 = iv.y - tv.y;
                    float sq = d0 * d0 + d1 * d1;
                    if (j < 5) stype += sq; else spar += sq;
                }
            }
        }
    }
    __syncthreads();    // stash complete

    // ---- per-row CE + param correction from LDS (one row per lane of wave 0) ----
    float nll = 0.0f, corr = 0.0f;
    if (tid < ROWS_PER_BLOCK && ((b >> tid) & 1ull)) {
        float tt[N_TYPE], l[N_TYPE];
        #pragma unroll
        for (int j = 0; j < N_TYPE; ++j) { tt[j] = s_tg[tid][j]; l[j] = s_in[tid][j]; }
        int ti = 0; float best = tt[0];
        #pragma unroll
        for (int j = 1; j < N_TYPE; ++j) { if (tt[j] > best) { best = tt[j]; ti = j; } }
        float m = l[0];
        #pragma unroll
        for (int j = 1; j < N_TYPE; ++j) m = fmaxf(m, l[j]);
        float s = 0.0f;
        #pragma unroll
        for (int j = 0; j < N_TYPE; ++j) s += __expf(l[j] - m);
        nll = __logf(s) + m - l[ti];
        // replaced params {ti, ti+1, ti+2} (ti<=9, no wrap) contribute 0 in the
        // reference; the bulk sum covers all 12 -> record the subtraction.
        #pragma unroll
        for (int j = 0; j < 3; ++j) {
            float d = s_in[tid][N_TYPE + ti + j] - s_tg[tid][N_TYPE + ti + j];
            corr += d * d;
        }
    }

    // ---- block reduce: (svg = sall - stype - spar, par = spar, nll, corr) ----
    float vals[4] = {sall - stype - spar, spar, nll, corr};
    #pragma unroll
    for (int v = 0; v < 4; ++v) {
        float x = vals[v];
        #pragma unroll
        for (int off = 32; off > 0; off >>= 1) x += __shfl_down(x, off, 64);
        vals[v] = x;
    }
    if (lane == 0) {
        #pragma unroll
        for (int v = 0; v < 4; ++v) sred[wave][v] = vals[v];
    }
    __syncthreads();
    if (tid == 0) {
        float s0 = sred[0][0] + sred[1][0] + sred[2][0] + sred[3][0];
        float s1 = sred[0][1] + sred[1][1] + sred[2][1] + sred[3][1];
        float s2 = sred[0][2] + sred[1][2] + sred[2][2] + sred[3][2];
        float s3 = sred[0][3] + sred[1][3] + sred[2][3] + sred[3][3];
        part[blockIdx.x] = make_float4(s0, s1, s2, s3);
    }
}

// ---------------- Final reduce + loss composition ----------------
__global__ __launch_bounds__(256) void loss_final(const float4* __restrict__ part,
                                                  const unsigned* __restrict__ bitmap,
                                                  float* __restrict__ out,
                                                  int nb, int nw, int nrows) {
    __shared__ double sred[4][5];
    const int tid = threadIdx.x;
    double svg = 0.0, par = 0.0, nll = 0.0, corr = 0.0, cnt = 0.0;
    for (int i = tid; i < nb; i += 256) {
        float4 v = part[i];
        svg += v.x; par += v.y; nll += v.z; corr += v.w;
    }
    for (int i = tid; i < nw; i += 256)
        cnt += (double)__popc(bitmap[i]);
    double vals[5] = {svg, par, nll, corr, cnt};
    #pragma unroll
    for (int v = 0; v < 5; ++v) {
        double x = vals[v];
        #pragma unroll
        for (int off = 32; off > 0; off >>= 1) x += __shfl_down(x, off, 64);
        vals[v] = x;
    }
    const int wave = tid >> 6, lane = tid & 63;
    if (lane == 0) {
        #pragma unroll
        for (int v = 0; v < 5; ++v) sred[wave][v] = vals[v];
    }
    __syncthreads();
    if (tid == 0) {
        double S[5];
        #pragma unroll
        for (int v = 0; v < 5; ++v)
            S[v] = sred[0][v] + sred[1][v] + sred[2][v] + sred[3][v];
        double npad = (double)nrows - S[4];
        // padded rows: every svg/par element contributes (-100-(-1))^2 = 9801
        double svg_t = S[0] + 9801.0 * D_SVG * npad;
        double par_t = S[1] - S[3] + 9801.0 * N_PAR * npad;
        double loss = 10.0 * svg_t / ((double)nrows * D_SVG)
                    + 0.1  * S[2] / fmax(S[4], 1.0)
                    + 1.0  * par_t / ((double)nrows * N_PAR);
        out[0] = (float)loss;
    }
}

extern "C" void kernel_launch(void* const* d_in, const int* in_sizes, int n_in,
                              void* d_out, int out_size, void* d_ws, size_t ws_size,
                              hipStream_t stream) {
    const float* input  = (const float*)d_in[0];
    const float* target = (const float*)d_in[1];
    // d_in[2] (padding mask) unused: padded <=> target[row*278+256] == -1.0f
    float* out = (float*)d_out;

    const int nrows = in_sizes[0] / F_TOT;      // 131072 (divisible by 256)
    const int blk   = nrows / ROWS_PER_BLOCK;   // 2048
    const int nw    = nrows / 32;               // 4096 bitmap words
    const int blk_m = nrows / 256;              // 512

    float4*   part   = (float4*)d_ws;
    unsigned* bitmap = (unsigned*)((char*)d_ws + (size_t)blk * sizeof(float4));

    bitmap_kernel<<<blk_m, 256, 0, stream>>>(target, bitmap);
    fused_kernel<<<blk, THREADS, 0, stream>>>(input, target, bitmap, part);
    loss_final<<<1, 256, 0, stream>>>(part, bitmap, out, blk, nw, nrows);
}